// Round 3
// baseline (728.726 us; speedup 1.0000x reference)
//
#include <hip/hip_runtime.h>

typedef unsigned short u16;
typedef unsigned int u32;
typedef __attribute__((ext_vector_type(8))) short bf16x8;
typedef __attribute__((ext_vector_type(4))) float f32x4;

#define T_TOK 2048
#define H_DIM 1024
#define E_NUM 8
#define F_DIM 2816
#define BM 128
#define BN 64
#define BK 32
#define LDK 40
#define MAX_SLOTS 5120

// pack two fp32 -> two bf16 (round-half-up), lo in low 16 bits
__device__ __forceinline__ u32 pkbf(float hi, float lo) {
    u32 a = __float_as_uint(hi) + 0x8000u;
    u32 b = __float_as_uint(lo) + 0x8000u;
#if __has_builtin(__builtin_amdgcn_perm)
    return __builtin_amdgcn_perm(a, b, 0x07060302u);
#else
    return (a & 0xFFFF0000u) | (b >> 16);
#endif
}
__device__ __forceinline__ u16 f2bf(float f) {
    return (u16)((__float_as_uint(f) + 0x8000u) >> 16);
}

// ---------------- Router: logits, softmax, top-2, bucket scatter --------------
__global__ __launch_bounds__(64) void router_kernel(
    const float* __restrict__ x, const float* __restrict__ gw,
    float* __restrict__ logits_out, int* __restrict__ cnt,
    int* __restrict__ tok_list, float* __restrict__ wt_list)
{
    int t = blockIdx.x;
    int lane = threadIdx.x;
    const float* xr = x + (size_t)t * H_DIM;

    float acc[E_NUM];
#pragma unroll
    for (int e = 0; e < E_NUM; e++) acc[e] = 0.f;

    for (int j = 0; j < H_DIM / 64; j++) {
        int idx = j * 64 + lane;
        float xv = xr[idx];
#pragma unroll
        for (int e = 0; e < E_NUM; e++)
            acc[e] += xv * gw[e * H_DIM + idx];
    }
#pragma unroll
    for (int e = 0; e < E_NUM; e++) {
        float v = acc[e];
#pragma unroll
        for (int o = 32; o > 0; o >>= 1) v += __shfl_xor(v, o, 64);
        acc[e] = v;
    }
    if (lane == 0) {
#pragma unroll
        for (int e = 0; e < E_NUM; e++) logits_out[t * E_NUM + e] = acc[e];
        float m = acc[0];
#pragma unroll
        for (int e = 1; e < E_NUM; e++) m = fmaxf(m, acc[e]);
        float p[E_NUM], s = 0.f;
#pragma unroll
        for (int e = 0; e < E_NUM; e++) { p[e] = expf(acc[e] - m); s += p[e]; }
        float inv = 1.f / s;
#pragma unroll
        for (int e = 0; e < E_NUM; e++) p[e] *= inv;
        int i0 = 0;
#pragma unroll
        for (int e = 1; e < E_NUM; e++) if (p[e] > p[i0]) i0 = e;
        int i1 = (i0 == 0) ? 1 : 0;
#pragma unroll
        for (int e = 0; e < E_NUM; e++) if (e != i0 && p[e] > p[i1]) i1 = e;
        float w0 = p[i0], w1 = p[i1];
        float rs = 1.f / (w0 + w1);
        w0 *= rs; w1 *= rs;
        int s0 = atomicAdd(&cnt[i0], 1);
        tok_list[i0 * T_TOK + s0] = t; wt_list[i0 * T_TOK + s0] = w0;
        int s1 = atomicAdd(&cnt[i1], 1);
        tok_list[i1 * T_TOK + s1] = t; wt_list[i1 * T_TOK + s1] = w1;
    }
}

// ---------------- Padded prefix offsets (pad to BM=128) ----------------------
__global__ void offsets_kernel(const int* __restrict__ cnt, int* __restrict__ off)
{
    if (threadIdx.x == 0 && blockIdx.x == 0) {
        int s = 0;
        for (int e = 0; e < E_NUM; e++) {
            off[e] = s;
            s += ((cnt[e] + BM - 1) / BM) * BM;
        }
        off[E_NUM] = s;
    }
}

// ---------------- GEMM1: act = silu(x*w1) * (x*w3) * wt ----------------------
// Column-persistent: grid (F/BN, E); each block loops the expert's m-tiles.
__global__ __launch_bounds__(256, 2) void gemm1_kernel(
    const float* __restrict__ x, const float* __restrict__ w1,
    const float* __restrict__ w3, const int* __restrict__ cnt,
    const int* __restrict__ off, const int* __restrict__ tok_list,
    const float* __restrict__ wt_list, u16* __restrict__ act)
{
    int e = blockIdx.y;
    int n0 = blockIdx.x * BN;
    int c = cnt[e];
    int nmt = (c + BM - 1) / BM;
    int base_slot = off[e];

    __shared__ __align__(16) u16 As[BM][LDK];
    __shared__ __align__(16) u16 B1s[BN][LDK];
    __shared__ __align__(16) u16 B3s[BN][LDK];
    __shared__ int tok_s[BM];
    __shared__ float wt_s[BM];

    int tid = threadIdx.x;
    int w = tid >> 6, lane = tid & 63, q = lane >> 4, l15 = lane & 15;
    int wm = (w >> 1) * 64, wn = (w & 1) * 32;
    int arow = tid >> 1, koff = (tid & 1) * 16;   // A staging: 2 thr/row, 16 elems each
    int bn = lane, kseg = (tid >> 6) * 8;          // B staging: k-column of 8 per thread

    const size_t wofs = (size_t)e * H_DIM * F_DIM + n0 + bn;
    const float* w1p = w1 + wofs;
    const float* w3p = w3 + wofs;

    for (int mt = 0; mt < nmt; ++mt) {
        __syncthreads();
        if (tid < BM) {
            int tk = tok_list[e * T_TOK + mt * BM + tid];
            tok_s[tid] = tk;
            wt_s[tid] = (tk >= 0) ? wt_list[e * T_TOK + mt * BM + tid] : 0.f;
        }
        __syncthreads();
        int tokA = tok_s[arow];
        const float* xa = x + (size_t)(tokA < 0 ? 0 : tokA) * H_DIM + koff;

        f32x4 zero = {0.f, 0.f, 0.f, 0.f};
        f32x4 accg[4][2], accu[4][2];
#pragma unroll
        for (int tm = 0; tm < 4; tm++)
#pragma unroll
            for (int tn = 0; tn < 2; tn++) { accg[tm][tn] = zero; accu[tm][tn] = zero; }

        for (int k0 = 0; k0 < H_DIM; k0 += BK) {
            // ---- A: fp32 -> bf16 -> LDS (row-major, natural layout)
            uint4 qa0 = {0u,0u,0u,0u}, qa1 = {0u,0u,0u,0u};
            if (tokA >= 0) {
                const float4* p = (const float4*)(xa + k0);
                float4 f0 = p[0], f1 = p[1], f2 = p[2], f3 = p[3];
                qa0.x = pkbf(f0.y, f0.x); qa0.y = pkbf(f0.w, f0.z);
                qa0.z = pkbf(f1.y, f1.x); qa0.w = pkbf(f1.w, f1.z);
                qa1.x = pkbf(f2.y, f2.x); qa1.y = pkbf(f2.w, f2.z);
                qa1.z = pkbf(f3.y, f3.x); qa1.w = pkbf(f3.w, f3.z);
            }
            *(uint4*)&As[arow][koff] = qa0;
            *(uint4*)&As[arow][koff + 8] = qa1;

            // ---- B1/B3: per-thread k-column (coalesced across lanes), one b128 write
            {
                const float* bp = w1p + (size_t)(k0 + kseg) * F_DIM;
                float c0 = bp[0];          float c1 = bp[(size_t)F_DIM];
                float c2 = bp[2*(size_t)F_DIM]; float c3 = bp[3*(size_t)F_DIM];
                float c4 = bp[4*(size_t)F_DIM]; float c5 = bp[5*(size_t)F_DIM];
                float c6 = bp[6*(size_t)F_DIM]; float c7 = bp[7*(size_t)F_DIM];
                uint4 qb;
                qb.x = pkbf(c1, c0); qb.y = pkbf(c3, c2);
                qb.z = pkbf(c5, c4); qb.w = pkbf(c7, c6);
                *(uint4*)&B1s[bn][kseg] = qb;
            }
            {
                const float* bp = w3p + (size_t)(k0 + kseg) * F_DIM;
                float c0 = bp[0];          float c1 = bp[(size_t)F_DIM];
                float c2 = bp[2*(size_t)F_DIM]; float c3 = bp[3*(size_t)F_DIM];
                float c4 = bp[4*(size_t)F_DIM]; float c5 = bp[5*(size_t)F_DIM];
                float c6 = bp[6*(size_t)F_DIM]; float c7 = bp[7*(size_t)F_DIM];
                uint4 qb;
                qb.x = pkbf(c1, c0); qb.y = pkbf(c3, c2);
                qb.z = pkbf(c5, c4); qb.w = pkbf(c7, c6);
                *(uint4*)&B3s[bn][kseg] = qb;
            }
            __syncthreads();

            bf16x8 a[4], bb1[2], bb3[2];
#pragma unroll
            for (int tm = 0; tm < 4; tm++)
                a[tm] = *(const bf16x8*)&As[wm + tm * 16 + l15][q * 8];
#pragma unroll
            for (int tn = 0; tn < 2; tn++) {
                bb1[tn] = *(const bf16x8*)&B1s[wn + tn * 16 + l15][q * 8];
                bb3[tn] = *(const bf16x8*)&B3s[wn + tn * 16 + l15][q * 8];
            }
#pragma unroll
            for (int tm = 0; tm < 4; tm++)
#pragma unroll
                for (int tn = 0; tn < 2; tn++) {
                    accg[tm][tn] = __builtin_amdgcn_mfma_f32_16x16x32_bf16(a[tm], bb1[tn], accg[tm][tn], 0, 0, 0);
                    accu[tm][tn] = __builtin_amdgcn_mfma_f32_16x16x32_bf16(a[tm], bb3[tn], accu[tm][tn], 0, 0, 0);
                }
            __syncthreads();
        }

        int srow = base_slot + mt * BM;
#pragma unroll
        for (int tm = 0; tm < 4; tm++)
#pragma unroll
            for (int tn = 0; tn < 2; tn++) {
                int col = n0 + wn + tn * 16 + l15;
#pragma unroll
                for (int r = 0; r < 4; r++) {
                    int row = wm + tm * 16 + q * 4 + r;
                    float g = accg[tm][tn][r];
                    float u = accu[tm][tn][r];
                    float wt = wt_s[row];
                    float val = (g / (1.f + __expf(-g))) * u * wt;
                    act[(size_t)(srow + row) * F_DIM + col] = f2bf(val);
                }
            }
    }
}

// ---------------- GEMM2: out += act * w2 (atomic fp32 into d_out) ------------
// grid (H/BN, 2 m-halves, E); each block loops its half of the m-tiles.
__global__ __launch_bounds__(256, 2) void gemm2_kernel(
    const u16* __restrict__ act, const float* __restrict__ w2,
    const int* __restrict__ cnt, const int* __restrict__ off,
    const int* __restrict__ tok_list, float* __restrict__ outp)
{
    int e = blockIdx.z;
    int half = blockIdx.y;
    int n0 = blockIdx.x * BN;
    int c = cnt[e];
    int nmt = (c + BM - 1) / BM;
    int base_slot = off[e];

    __shared__ __align__(16) u16 As[BM][LDK];
    __shared__ __align__(16) u16 Bt[BN][LDK];
    __shared__ int tok_s[BM];

    int tid = threadIdx.x;
    int w = tid >> 6, lane = tid & 63, q = lane >> 4, l15 = lane & 15;
    int wm = (w >> 1) * 64, wn = (w & 1) * 32;
    int arow = tid >> 1, koff = (tid & 1) * 16;
    int bn = lane, kseg = (tid >> 6) * 8;

    const float* w2p = w2 + (size_t)e * F_DIM * H_DIM + n0 + bn;

    for (int mt = half; mt < nmt; mt += 2) {
        __syncthreads();
        if (tid < BM) tok_s[tid] = tok_list[e * T_TOK + mt * BM + tid];
        __syncthreads();

        f32x4 zero = {0.f, 0.f, 0.f, 0.f};
        f32x4 acc[4][2];
#pragma unroll
        for (int tm = 0; tm < 4; tm++)
#pragma unroll
            for (int tn = 0; tn < 2; tn++) acc[tm][tn] = zero;

        int srow = base_slot + mt * BM;
        const u16* ap = act + (size_t)(srow + arow) * F_DIM + koff;

        for (int k0 = 0; k0 < F_DIM; k0 += BK) {
            uint4 qa0 = *(const uint4*)(ap + k0);
            uint4 qa1 = *(const uint4*)(ap + k0 + 8);
            *(uint4*)&As[arow][koff] = qa0;
            *(uint4*)&As[arow][koff + 8] = qa1;

            const float* bp = w2p + (size_t)(k0 + kseg) * H_DIM;
            float c0 = bp[0];            float c1 = bp[H_DIM];
            float c2 = bp[2*H_DIM];      float c3 = bp[3*H_DIM];
            float c4 = bp[4*H_DIM];      float c5 = bp[5*H_DIM];
            float c6 = bp[6*H_DIM];      float c7 = bp[7*H_DIM];
            uint4 qb;
            qb.x = pkbf(c1, c0); qb.y = pkbf(c3, c2);
            qb.z = pkbf(c5, c4); qb.w = pkbf(c7, c6);
            *(uint4*)&Bt[bn][kseg] = qb;
            __syncthreads();

            bf16x8 a[4], b[2];
#pragma unroll
            for (int tm = 0; tm < 4; tm++)
                a[tm] = *(const bf16x8*)&As[wm + tm * 16 + l15][q * 8];
#pragma unroll
            for (int tn = 0; tn < 2; tn++)
                b[tn] = *(const bf16x8*)&Bt[wn + tn * 16 + l15][q * 8];
#pragma unroll
            for (int tm = 0; tm < 4; tm++)
#pragma unroll
                for (int tn = 0; tn < 2; tn++)
                    acc[tm][tn] = __builtin_amdgcn_mfma_f32_16x16x32_bf16(a[tm], b[tn], acc[tm][tn], 0, 0, 0);
            __syncthreads();
        }

#pragma unroll
        for (int tm = 0; tm < 4; tm++)
#pragma unroll
            for (int tn = 0; tn < 2; tn++) {
                int col = n0 + wn + tn * 16 + l15;
#pragma unroll
                for (int r = 0; r < 4; r++) {
                    int row = wm + tm * 16 + q * 4 + r;
                    int tok = tok_s[row];
                    if (tok >= 0)
                        atomicAdd(&outp[(size_t)tok * H_DIM + col], acc[tm][tn][r]);
                }
            }
    }
}

extern "C" void kernel_launch(void* const* d_in, const int* in_sizes, int n_in,
                              void* d_out, int out_size, void* d_ws, size_t ws_size,
                              hipStream_t stream) {
    const float* x  = (const float*)d_in[0];
    const float* gw = (const float*)d_in[1];
    const float* w1 = (const float*)d_in[2];
    const float* w3 = (const float*)d_in[3];
    const float* w2 = (const float*)d_in[4];
    float* out = (float*)d_out;

    char* ws = (char*)d_ws;
    int*   cnt      = (int*)(ws);                  // 64 B
    int*   off      = (int*)(ws + 64);             // 64 B (9 ints)
    int*   tok_list = (int*)(ws + 128);            // 64 KiB
    float* wt_list  = (float*)(ws + 128 + 65536);  // 64 KiB
    u16*   act      = (u16*)(ws + 131200);         // MAX_SLOTS*F_DIM*2 = ~27.5 MiB

    hipMemsetAsync(cnt, 0, 64, stream);
    hipMemsetAsync(tok_list, 0xFF, E_NUM * T_TOK * sizeof(int), stream);
    hipMemsetAsync(out, 0, (size_t)T_TOK * H_DIM * sizeof(float), stream);

    float* logits_out = out + (size_t)T_TOK * H_DIM;
    router_kernel<<<T_TOK, 64, 0, stream>>>(x, gw, logits_out, cnt, tok_list, wt_list);
    offsets_kernel<<<1, 64, 0, stream>>>(cnt, off);
    gemm1_kernel<<<dim3(F_DIM / BN, E_NUM), 256, 0, stream>>>(
        x, w1, w3, cnt, off, tok_list, wt_list, act);
    gemm2_kernel<<<dim3(H_DIM / BN, 2, E_NUM), 256, 0, stream>>>(
        act, w2, cnt, off, tok_list, out);
}